// Round 3
// baseline (80.182 us; speedup 1.0000x reference)
//
#include <hip/hip_runtime.h>
#include <hip/hip_bf16.h>

// Problem constants (from reference)
constexpr int S = 256;          // N_SINES
constexpr int N = 512;          // control points
constexpr int R = 32;           // RESAMPLING_FACTOR
constexpr int OUT_N = N * R;    // 16384 output samples per batch

// ---------------------------------------------------------------------------
// Kernel 1 (prep): per-(b,s) block-prefix scan + pack/transpose.
//
// G[n] = 16*f0 + sum_{m<n} 16*(f_m + f_{m+1})  (Hz-samples; exact closed form
// of the reference's cumsum at block boundaries). Scan in fp64 (G up to ~8e7;
// f32 would destroy the fractional phase). Then reduce mod 44100 here, once:
//   gfrac = frac(G / 44100)  in [0,1) revolutions, stored f32.
// Output layout is TRANSPOSED to [b][n][s] and packed so the synth kernel's
// inner s-loop is contiguous and needs only 2 load instrs per sine:
//   P4[(b*N+n)*S+s] = {gfrac, f_n, f_{n+1}-f_n, a_n},  P1[...] = a_{n+1}-a_n
// One block per row (b*S+s), 512 threads, Hillis-Steele scan in LDS (fp64).
// ---------------------------------------------------------------------------
__global__ __launch_bounds__(512) void prep_kernel(
    const float* __restrict__ freq, const float* __restrict__ amp,
    float4* __restrict__ P4, float* __restrict__ P1) {
  const int row = blockIdx.x;          // b*S + s
  const int n = threadIdx.x;           // 0..511
  const int b = row / S;
  const int s = row - b * S;
  const float* f = freq + (size_t)row * N;
  const float* a = amp  + (size_t)row * N;

  const float fn  = f[n];
  const float fn1 = (n < N - 1) ? f[n + 1] : fn;   // clamped
  const float an  = a[n];
  const float an1 = (n < N - 1) ? a[n + 1] : an;

  __shared__ double sh[N];
  sh[n] = (n < N - 1) ? 16.0 * ((double)fn + (double)fn1) : 0.0;
  __syncthreads();

  for (int off = 1; off < N; off <<= 1) {
    double add = (n >= off) ? sh[n - off] : 0.0;
    __syncthreads();
    sh[n] += add;
    __syncthreads();
  }

  const double G = 16.0 * (double)f[0] + ((n == 0) ? 0.0 : sh[n - 1]);
  double q = G * (1.0 / 44100.0);      // revolutions (2*pi/FS cancels)
  q -= floor(q);                       // frac -> [0,1), exact to ~2e-13
  const float gfrac = (float)q;

  const size_t o = ((size_t)(b * N + n)) * S + s;
  P4[o] = make_float4(gfrac, fn, fn1 - fn, an);
  P1[o] = an1 - an;
}

// ---------------------------------------------------------------------------
// Kernel 2 (synth): all-f32 inner loop.
// Block = 64 consecutive output samples of one batch; 4 waves each cover 64
// of the 256 sines (contiguous s-chunk => contiguous float4 stream, L1-hot),
// then LDS-reduce 4 partials.
//
// For sample j: r (revolutions) =
//   j <  16   : (j+1)*f_0/FS                          (n=0,  gsel=0, wa=0)
//   mid       : gfrac[n] + (k+1)*f_n/FS + (k+1)^2/64 * df_n/FS
//               n=(j-16)>>5, k=(j-16)&31, wa=(k+0.5)/32
//   j >= 16368: gfrac[511] + t*f_511/FS, t=j-16367     (n=511, wa=0)
// signal = sum_s (a_n + da_n*wa) * sin(2*pi*frac(r))  via v_sin_f32.
// ---------------------------------------------------------------------------
__global__ __launch_bounds__(256) void synth_kernel(
    const float4* __restrict__ P4, const float* __restrict__ P1,
    float* __restrict__ out) {
  const int tid = threadIdx.x;
  const int split = tid >> 6;                 // wave id 0..3 -> s-chunk
  const int samp = tid & 63;
  const int gid = blockIdx.x * 64 + samp;     // global output sample id
  const int b = gid >> 14;                    // / OUT_N
  const int j = gid & (OUT_N - 1);

  int n;
  float c1, c2, gsel, wa;
  if (j < 16) {                               // leading clip region
    n = 0; c1 = (float)(j + 1); c2 = 0.0f; gsel = 0.0f; wa = 0.0f;
  } else if (j >= OUT_N - 16) {               // trailing clip region
    n = N - 1; c1 = (float)(j - (OUT_N - 16) + 1); c2 = 0.0f; gsel = 1.0f; wa = 0.0f;
  } else {
    const int jj = j - 16;
    n = jj >> 5;
    const int k = jj & 31;
    c1 = (float)(k + 1);
    c2 = (float)((k + 1) * (k + 1)) * (1.0f / 64.0f);
    gsel = 1.0f;
    wa = ((float)k + 0.5f) * (1.0f / 32.0f);
  }
  const float inv_fs = 1.0f / 44100.0f;
  c1 *= inv_fs;                               // rev per Hz
  c2 *= inv_fs;

  const size_t base = ((size_t)(b * N + n)) * S;
  const float4* __restrict__ p4 = P4 + base;
  const float*  __restrict__ p1 = P1 + base;

  float acc = 0.0f;
  const int s0 = split * (S / 4);
  #pragma unroll 8
  for (int s = s0; s < s0 + S / 4; ++s) {
    const float4 v = p4[s];                   // {gfrac, fn, df, an}
    const float da = p1[s];
    float r = fmaf(c2, v.z, fmaf(c1, v.y, v.x * gsel));
    r -= floorf(r);                           // frac -> [0,1) revolutions
    const float sv = __builtin_amdgcn_sinf(r);// sin(2*pi*r)
    const float av = fmaf(da, wa, v.w);
    acc = fmaf(av, sv, acc);
  }

  __shared__ float red[256];
  red[tid] = acc;
  __syncthreads();
  if (tid < 64) {
    out[gid] = red[tid] + red[tid + 64] + red[tid + 128] + red[tid + 192];
  }
}

// ---------------------------------------------------------------------------
extern "C" void kernel_launch(void* const* d_in, const int* in_sizes, int n_in,
                              void* d_out, int out_size, void* d_ws, size_t ws_size,
                              hipStream_t stream) {
  const float* freq = (const float*)d_in[0];
  const float* amp  = (const float*)d_in[1];
  float* out = (float*)d_out;

  const int B = in_sizes[0] / (S * N);        // 4
  // Workspace layout: P4 [B*N*S] float4 (8 MiB at B=4), then P1 [B*N*S] float
  float4* P4 = (float4*)d_ws;
  float*  P1 = (float*)((char*)d_ws + (size_t)B * N * S * sizeof(float4));

  prep_kernel<<<dim3(B * S), dim3(512), 0, stream>>>(freq, amp, P4, P1);
  synth_kernel<<<dim3(B * OUT_N / 64), dim3(256), 0, stream>>>(P4, P1, out);
}